// Round 1
// baseline (4932.986 us; speedup 1.0000x reference)
//
#include <hip/hip_runtime.h>

#define NN 50000      // nodes
#define NE 250000     // edges
#define DD 256        // feature dim
#define NREL 8        // relations
#define NL 3          // layers

#define BM 128
#define BN 128
#define BK 16
// 256 threads/block, each thread computes an 8x8 micro-tile.

__global__ void zero_small(int* counts, int* cursors) {
    int t = threadIdx.x;
    if (t < NREL) { counts[t] = 0; cursors[t] = 0; }
}

__global__ void hist_kernel(const int* __restrict__ et, int* __restrict__ counts) {
    int e = blockIdx.x * blockDim.x + threadIdx.x;
    if (e < NE) atomicAdd(&counts[et[e]], 1);
}

__global__ void scan_kernel(const int* __restrict__ counts, int* __restrict__ offsets,
                            int* __restrict__ cursors) {
    if (threadIdx.x == 0 && blockIdx.x == 0) {
        int s = 0;
        for (int r = 0; r < NREL; ++r) { offsets[r] = s; cursors[r] = s; s += counts[r]; }
        offsets[NREL] = s;
    }
}

__global__ void bucket_kernel(const int* __restrict__ ei, const int* __restrict__ et,
                              int* __restrict__ cursors, int* __restrict__ ssrc,
                              int* __restrict__ sdst) {
    int e = blockIdx.x * blockDim.x + threadIdx.x;
    if (e < NE) {
        int r = et[e];
        int p = atomicAdd(&cursors[r], 1);
        ssrc[p] = ei[e];
        sdst[p] = ei[NE + e];
    }
}

// ---------------- root GEMM: C = A @ W + bias (full overwrite) ----------------
__global__ __launch_bounds__(256)
void root_gemm(const float* __restrict__ A, const float* __restrict__ W,
               const float* __restrict__ bias, float* __restrict__ C)
{
    __shared__ float As[BK][BM + 4];   // [k][row], pad 4 keeps f4 alignment + spreads banks
    __shared__ float Bs[BK][BN];       // [k][col]

    const int tid = threadIdx.x;
    const int tc = tid & 15;           // output col group (cols tc*4 and 64+tc*4)
    const int tr = tid >> 4;           // output row group (rows tr*8 .. tr*8+7)
    const int m0 = blockIdx.x * BM;
    const int n0 = blockIdx.y * BN;

    const int a4 = tid & 3;            // which float4 of the 16-wide k-slice
    const int ar = tid >> 2;           // A row within tile (+64)
    const int b4 = tid & 31;           // B float4 col index
    const int br = tid >> 5;           // B row (+8)

    float acc[8][8];
#pragma unroll
    for (int i = 0; i < 8; ++i)
#pragma unroll
        for (int j = 0; j < 8; ++j) acc[i][j] = 0.f;

    for (int kt = 0; kt < DD / BK; ++kt) {
        const int k0 = kt * BK;
#pragma unroll
        for (int t = 0; t < 2; ++t) {
            int i = ar + 64 * t;
            int row = m0 + i;
            float4 v = make_float4(0.f, 0.f, 0.f, 0.f);
            if (row < NN) v = *(const float4*)&A[(size_t)row * DD + k0 + a4 * 4];
            As[a4 * 4 + 0][i] = v.x;
            As[a4 * 4 + 1][i] = v.y;
            As[a4 * 4 + 2][i] = v.z;
            As[a4 * 4 + 3][i] = v.w;
        }
#pragma unroll
        for (int t = 0; t < 2; ++t) {
            int r = br + 8 * t;
            float4 v = *(const float4*)&W[(size_t)(k0 + r) * DD + n0 + b4 * 4];
            *(float4*)&Bs[r][b4 * 4] = v;
        }
        __syncthreads();
#pragma unroll
        for (int k = 0; k < BK; ++k) {
            float4 a0 = *(const float4*)&As[k][tr * 8];
            float4 a1 = *(const float4*)&As[k][tr * 8 + 4];
            float4 b0 = *(const float4*)&Bs[k][tc * 4];
            float4 b1 = *(const float4*)&Bs[k][64 + tc * 4];
            float a[8] = {a0.x, a0.y, a0.z, a0.w, a1.x, a1.y, a1.z, a1.w};
            float b[8] = {b0.x, b0.y, b0.z, b0.w, b1.x, b1.y, b1.z, b1.w};
#pragma unroll
            for (int i = 0; i < 8; ++i)
#pragma unroll
                for (int j = 0; j < 8; ++j) acc[i][j] += a[i] * b[j];
        }
        __syncthreads();
    }

#pragma unroll
    for (int i = 0; i < 8; ++i) {
        int row = m0 + tr * 8 + i;
        if (row < NN) {
            float4 o0, o1;
            o0.x = acc[i][0] + bias[n0 + tc * 4 + 0];
            o0.y = acc[i][1] + bias[n0 + tc * 4 + 1];
            o0.z = acc[i][2] + bias[n0 + tc * 4 + 2];
            o0.w = acc[i][3] + bias[n0 + tc * 4 + 3];
            o1.x = acc[i][4] + bias[n0 + 64 + tc * 4 + 0];
            o1.y = acc[i][5] + bias[n0 + 64 + tc * 4 + 1];
            o1.z = acc[i][6] + bias[n0 + 64 + tc * 4 + 2];
            o1.w = acc[i][7] + bias[n0 + 64 + tc * 4 + 3];
            *(float4*)&C[(size_t)row * DD + n0 + tc * 4] = o0;
            *(float4*)&C[(size_t)row * DD + n0 + 64 + tc * 4] = o1;
        }
    }
}

// -------- edge GEMM: out[dst] += (x[src] @ W_rel[rel]) via atomics --------
__global__ __launch_bounds__(256)
void edge_gemm(const float* __restrict__ X, const float* __restrict__ Wl,
               const int* __restrict__ ssrc, const int* __restrict__ sdst,
               const int* __restrict__ offsets, float* __restrict__ out)
{
    __shared__ float As[BK][BM + 4];
    __shared__ float Bs[BK][BN];
    __shared__ int srcs[BM];
    __shared__ int dsts[BM];

    // map blockIdx.x -> (relation, tile-within-relation)
    const int t = blockIdx.x;
    int rel = -1, base = 0, cnt = 0, accT = 0;
#pragma unroll
    for (int r = 0; r < NREL; ++r) {
        int s = offsets[r], e = offsets[r + 1];
        int nt = (e - s + BM - 1) / BM;
        if (rel < 0 && t < accT + nt) {
            rel = r;
            base = s + (t - accT) * BM;
            cnt = min(BM, e - base);
        }
        accT += nt;
    }
    if (rel < 0) return;

    const int tid = threadIdx.x;
    if (tid < BM) {
        int idx = base + tid;
        srcs[tid] = (tid < cnt) ? ssrc[idx] : 0;
        dsts[tid] = (tid < cnt) ? sdst[idx] : 0;
    }
    __syncthreads();

    const float* W = Wl + (size_t)rel * DD * DD;

    const int tc = tid & 15;
    const int tr = tid >> 4;
    const int n0 = blockIdx.y * BN;
    const int a4 = tid & 3;
    const int ar = tid >> 2;
    const int b4 = tid & 31;
    const int br = tid >> 5;

    float acc[8][8];
#pragma unroll
    for (int i = 0; i < 8; ++i)
#pragma unroll
        for (int j = 0; j < 8; ++j) acc[i][j] = 0.f;

    for (int kt = 0; kt < DD / BK; ++kt) {
        const int k0 = kt * BK;
#pragma unroll
        for (int t2 = 0; t2 < 2; ++t2) {
            int i = ar + 64 * t2;
            int row = srcs[i];  // always a valid node (0 for pad slots)
            float4 v = *(const float4*)&X[(size_t)row * DD + k0 + a4 * 4];
            As[a4 * 4 + 0][i] = v.x;
            As[a4 * 4 + 1][i] = v.y;
            As[a4 * 4 + 2][i] = v.z;
            As[a4 * 4 + 3][i] = v.w;
        }
#pragma unroll
        for (int t2 = 0; t2 < 2; ++t2) {
            int r = br + 8 * t2;
            float4 v = *(const float4*)&W[(size_t)(k0 + r) * DD + n0 + b4 * 4];
            *(float4*)&Bs[r][b4 * 4] = v;
        }
        __syncthreads();
#pragma unroll
        for (int k = 0; k < BK; ++k) {
            float4 a0 = *(const float4*)&As[k][tr * 8];
            float4 a1 = *(const float4*)&As[k][tr * 8 + 4];
            float4 b0 = *(const float4*)&Bs[k][tc * 4];
            float4 b1 = *(const float4*)&Bs[k][64 + tc * 4];
            float a[8] = {a0.x, a0.y, a0.z, a0.w, a1.x, a1.y, a1.z, a1.w};
            float b[8] = {b0.x, b0.y, b0.z, b0.w, b1.x, b1.y, b1.z, b1.w};
#pragma unroll
            for (int i = 0; i < 8; ++i)
#pragma unroll
                for (int j = 0; j < 8; ++j) acc[i][j] += a[i] * b[j];
        }
        __syncthreads();
    }

#pragma unroll
    for (int i = 0; i < 8; ++i) {
        int slot = tr * 8 + i;
        if (slot < cnt) {
            int d = dsts[slot];
            float* o0 = &out[(size_t)d * DD + n0 + tc * 4];
            float* o1 = &out[(size_t)d * DD + n0 + 64 + tc * 4];
            atomicAdd(&o0[0], acc[i][0]);
            atomicAdd(&o0[1], acc[i][1]);
            atomicAdd(&o0[2], acc[i][2]);
            atomicAdd(&o0[3], acc[i][3]);
            atomicAdd(&o1[0], acc[i][4]);
            atomicAdd(&o1[1], acc[i][5]);
            atomicAdd(&o1[2], acc[i][6]);
            atomicAdd(&o1[3], acc[i][7]);
        }
    }
}

__global__ void relu_kernel(float4* __restrict__ p, int n4) {
    int i = blockIdx.x * blockDim.x + threadIdx.x;
    int stride = gridDim.x * blockDim.x;
    for (; i < n4; i += stride) {
        float4 v = p[i];
        v.x = v.x > 0.f ? v.x : 0.f;
        v.y = v.y > 0.f ? v.y : 0.f;
        v.z = v.z > 0.f ? v.z : 0.f;
        v.w = v.w > 0.f ? v.w : 0.f;
        p[i] = v;
    }
}

extern "C" void kernel_launch(void* const* d_in, const int* in_sizes, int n_in,
                              void* d_out, int out_size, void* d_ws, size_t ws_size,
                              hipStream_t stream)
{
    const float* x      = (const float*)d_in[0];
    const int*   ei     = (const int*)d_in[1];   // [2][NE]: src row then dst row
    const int*   et     = (const int*)d_in[2];   // [NE]
    const float* W_rel  = (const float*)d_in[3]; // [NL][NREL][DD][DD]
    const float* W_root = (const float*)d_in[4]; // [NL][DD][DD]
    const float* bias   = (const float*)d_in[5]; // [NL][DD]
    float* out = (float*)d_out;

    float* bufA   = (float*)d_ws;                       // NN*DD floats (51.2 MB)
    int*   ssrc   = (int*)(bufA + (size_t)NN * DD);     // NE
    int*   sdst   = ssrc + NE;                          // NE
    int*   counts = sdst + NE;                          // NREL
    int*   offs   = counts + NREL;                      // NREL+1
    int*   curs   = offs + NREL + 1;                    // NREL

    // counting sort of edges by relation (recomputed each call; deterministic work)
    zero_small<<<1, 64, 0, stream>>>(counts, curs);
    hist_kernel<<<(NE + 255) / 256, 256, 0, stream>>>(et, counts);
    scan_kernel<<<1, 64, 0, stream>>>(counts, offs, curs);
    bucket_kernel<<<(NE + 255) / 256, 256, 0, stream>>>(ei, et, curs, ssrc, sdst);

    const int ntiles = (NE + BM - 1) / BM + NREL;       // upper bound on edge tiles

    const float* cur = x;
    for (int l = 0; l < NL; ++l) {
        float* dst = (l == 0) ? out : (l == 1) ? bufA : out;
        root_gemm<<<dim3((NN + BM - 1) / BM, DD / BN), 256, 0, stream>>>(
            cur, W_root + (size_t)l * DD * DD, bias + (size_t)l * DD, dst);
        edge_gemm<<<dim3(ntiles, DD / BN), 256, 0, stream>>>(
            cur, W_rel + (size_t)l * NREL * DD * DD, ssrc, sdst, offs, dst);
        relu_kernel<<<1024, 256, 0, stream>>>((float4*)dst, NN * DD / 4);
        cur = dst;
    }
}

// Round 5
// 813.794 us; speedup vs baseline: 6.0617x; 6.0617x over previous
//
#include <hip/hip_runtime.h>

#define NN 50000      // nodes
#define NE 250000     // edges
#define DD 256        // feature dim
#define NREL 8        // relations
#define NL 3          // layers

#define CHUNK 4096
#define NSB ((NE + CHUNK - 1) / CHUNK)   // 62 sort blocks

typedef __attribute__((ext_vector_type(8))) short short8;
typedef __attribute__((ext_vector_type(4))) float floatx4;

#if __has_builtin(__builtin_amdgcn_global_load_lds)
#define GLOAD16(g, l) __builtin_amdgcn_global_load_lds( \
    (__attribute__((address_space(1))) void*)(void*)(g), \
    (__attribute__((address_space(3))) void*)(void*)(l), 16, 0, 0)
#else
#define GLOAD16(g, l) do { *(uint4*)(l) = *(const uint4*)(g); } while (0)
#endif

__device__ inline unsigned short f2bf(float f) {
    unsigned int u = __builtin_bit_cast(unsigned int, f);
    u += 0x7FFFu + ((u >> 16) & 1u);          // round-to-nearest-even
    return (unsigned short)(u >> 16);
}

// ---------------- contention-free counting sort (by relation) ----------------
__global__ void hist_block(const int* __restrict__ et, int* __restrict__ blockCounts) {
    __shared__ int h[NREL];
    const int b = blockIdx.x;
    if (threadIdx.x < NREL) h[threadIdx.x] = 0;
    __syncthreads();
    const int base = b * CHUNK;
    const int end = min(base + CHUNK, NE);
    for (int e = base + threadIdx.x; e < end; e += blockDim.x)
        atomicAdd(&h[et[e]], 1);              // LDS atomic — block-local only
    __syncthreads();
    if (threadIdx.x < NREL) blockCounts[b * NREL + threadIdx.x] = h[threadIdx.x];
}

__global__ void scan_blocks(const int* __restrict__ blockCounts,
                            int* __restrict__ blockOffs, int* __restrict__ offs) {
    if (threadIdx.x == 0 && blockIdx.x == 0) {
        int relTot[NREL];
#pragma unroll
        for (int r = 0; r < NREL; ++r) relTot[r] = 0;
        for (int b = 0; b < NSB; ++b)
#pragma unroll
            for (int r = 0; r < NREL; ++r) relTot[r] += blockCounts[b * NREL + r];
        int s = 0;
        int relStart[NREL];
#pragma unroll
        for (int r = 0; r < NREL; ++r) { offs[r] = s; relStart[r] = s; s += relTot[r]; }
        offs[NREL] = s;
        for (int b = 0; b < NSB; ++b)
#pragma unroll
            for (int r = 0; r < NREL; ++r) {
                blockOffs[b * NREL + r] = relStart[r];
                relStart[r] += blockCounts[b * NREL + r];
            }
    }
}

__global__ void scatter_block(const int* __restrict__ ei, const int* __restrict__ et,
                              const int* __restrict__ blockOffs,
                              int* __restrict__ ssrc, int* __restrict__ sdst) {
    __shared__ int cur[NREL];
    const int b = blockIdx.x;
    if (threadIdx.x < NREL) cur[threadIdx.x] = blockOffs[b * NREL + threadIdx.x];
    __syncthreads();
    const int base = b * CHUNK;
    const int end = min(base + CHUNK, NE);
    for (int e = base + threadIdx.x; e < end; e += blockDim.x) {
        int r = et[e];
        int p = atomicAdd(&cur[r], 1);        // LDS atomic
        ssrc[p] = ei[e];
        sdst[p] = ei[NE + e];
    }
}

// ------------- weight transpose + fp32->bf16 (out[m][e][d] = in[m][d][e]) -------------
__global__ void transpose_bf16(const float* __restrict__ src, unsigned short* __restrict__ dst) {
    __shared__ float t[32][33];
    const size_t mb = (size_t)blockIdx.x * DD * DD;
    const int d0 = blockIdx.y * 32, e0 = blockIdx.z * 32;
    const int tx = threadIdx.x, ty = threadIdx.y;
#pragma unroll
    for (int i = 0; i < 4; ++i)
        t[ty + 8 * i][tx] = src[mb + (size_t)(d0 + ty + 8 * i) * DD + e0 + tx];
    __syncthreads();
#pragma unroll
    for (int i = 0; i < 4; ++i)
        dst[mb + (size_t)(e0 + ty + 8 * i) * DD + d0 + tx] = f2bf(t[tx][ty + 8 * i]);
}

// ---------------- fp32 -> bf16 (layer-0 input) ----------------
__global__ void conv_bf16(const float4* __restrict__ s, ushort4* __restrict__ d, int n4) {
    int i = blockIdx.x * blockDim.x + threadIdx.x;
    const int stride = gridDim.x * blockDim.x;
    for (; i < n4; i += stride) {
        float4 v = s[i];
        d[i] = make_ushort4(f2bf(v.x), f2bf(v.y), f2bf(v.z), f2bf(v.w));
    }
}

// ---------------- relu in-place + bf16 copy for next layer ----------------
__global__ void relu_convert(float4* __restrict__ p, ushort4* __restrict__ xb, int n4) {
    int i = blockIdx.x * blockDim.x + threadIdx.x;
    const int stride = gridDim.x * blockDim.x;
    for (; i < n4; i += stride) {
        float4 v = p[i];
        v.x = v.x > 0.f ? v.x : 0.f;
        v.y = v.y > 0.f ? v.y : 0.f;
        v.z = v.z > 0.f ? v.z : 0.f;
        v.w = v.w > 0.f ? v.w : 0.f;
        p[i] = v;
        xb[i] = make_ushort4(f2bf(v.x), f2bf(v.y), f2bf(v.z), f2bf(v.w));
    }
}

// ---------------- root GEMM (MFMA): C = Xb @ W^T' + bias, full overwrite ----------------
// WT is [DD][DD] bf16 with WT[e][d] = W[d][e]  (B-frag reads K-contiguous rows of WT)
__global__ __launch_bounds__(256)
void root_gemm_mfma(const unsigned short* __restrict__ Xb, const unsigned short* __restrict__ WT,
                    const float* __restrict__ bias, float* __restrict__ C)
{
    __shared__ unsigned short As[128][32];
    __shared__ unsigned short Bs[128][32];
    const int tid = threadIdx.x;
    const int lane = tid & 63;
    const int w = tid >> 6;
    const int wr = w >> 1, wc = w & 1;     // 2x2 wave grid, 64x64 output per wave
    const int m0 = blockIdx.x * 128;
    const int n0 = blockIdx.y * 128;

    const int srow = tid >> 2;             // staging: 0..63
    const int sq = tid & 3;                // 16B quarter of a 64B k-slice

    floatx4 acc[4][4] = {};

    for (int kt = 0; kt < DD / 32; ++kt) {
        const int k0 = kt * 32;
        {
            int r0 = min(m0 + srow, NN - 1);
            int r1 = min(m0 + srow + 64, NN - 1);
            GLOAD16(&Xb[(size_t)r0 * DD + k0 + sq * 8], &As[srow][sq * 8]);
            GLOAD16(&Xb[(size_t)r1 * DD + k0 + sq * 8], &As[srow + 64][sq * 8]);
            GLOAD16(&WT[(size_t)(n0 + srow) * DD + k0 + sq * 8], &Bs[srow][sq * 8]);
            GLOAD16(&WT[(size_t)(n0 + srow + 64) * DD + k0 + sq * 8], &Bs[srow + 64][sq * 8]);
        }
        __syncthreads();
        short8 a[4], b[4];
#pragma unroll
        for (int mi = 0; mi < 4; ++mi)
            a[mi] = *(const short8*)&As[wr * 64 + mi * 16 + (lane & 15)][(lane >> 4) * 8];
#pragma unroll
        for (int ni = 0; ni < 4; ++ni)
            b[ni] = *(const short8*)&Bs[wc * 64 + ni * 16 + (lane & 15)][(lane >> 4) * 8];
#pragma unroll
        for (int mi = 0; mi < 4; ++mi)
#pragma unroll
            for (int ni = 0; ni < 4; ++ni)
                acc[mi][ni] = __builtin_amdgcn_mfma_f32_16x16x32_bf16(a[mi], b[ni], acc[mi][ni], 0, 0, 0);
        __syncthreads();
    }

    const int cq = lane >> 4;              // C/D: row=(lane>>4)*4+q, col=lane&15 (m89)
    const int cn = lane & 15;
#pragma unroll
    for (int mi = 0; mi < 4; ++mi) {
#pragma unroll
        for (int q = 0; q < 4; ++q) {
            int row = m0 + wr * 64 + mi * 16 + cq * 4 + q;
            if (row < NN) {
#pragma unroll
                for (int ni = 0; ni < 4; ++ni) {
                    int col = n0 + wc * 64 + ni * 16 + cn;
                    C[(size_t)row * DD + col] = acc[mi][ni][q] + bias[col];
                }
            }
        }
    }
}

// -------- edge GEMM (MFMA): out[dst] += (Xb[src] @ W_rel^T'[rel]) via atomics --------
__global__ __launch_bounds__(256)
void edge_gemm_mfma(const unsigned short* __restrict__ Xb, const unsigned short* __restrict__ WTl,
                    const int* __restrict__ ssrc, const int* __restrict__ sdst,
                    const int* __restrict__ offsets, float* __restrict__ out)
{
    __shared__ unsigned short As[128][32];
    __shared__ unsigned short Bs[128][32];
    __shared__ int srcs[128];
    __shared__ int dsts[128];

    // map blockIdx.x -> (relation, tile-within-relation)
    const int t = blockIdx.x;
    int rel = -1, base = 0, cnt = 0, accT = 0;
#pragma unroll
    for (int r = 0; r < NREL; ++r) {
        int s = offsets[r], e = offsets[r + 1];
        int nt = (e - s + 127) / 128;
        if (rel < 0 && t < accT + nt) {
            rel = r;
            base = s + (t - accT) * 128;
            cnt = min(128, e - base);
        }
        accT += nt;
    }
    if (rel < 0) return;

    const int tid = threadIdx.x;
    if (tid < 128) {
        int idx = base + tid;
        srcs[tid] = (tid < cnt) ? ssrc[idx] : 0;
        dsts[tid] = (tid < cnt) ? sdst[idx] : 0;
    }
    __syncthreads();

    const unsigned short* WT = WTl + (size_t)rel * DD * DD;

    const int lane = tid & 63;
    const int w = tid >> 6;
    const int wr = w >> 1, wc = w & 1;
    const int n0 = blockIdx.y * 128;
    const int srow = tid >> 2;
    const int sq = tid & 3;

    floatx4 acc[4][4] = {};

    for (int kt = 0; kt < DD / 32; ++kt) {
        const int k0 = kt * 32;
        {
            int r0 = srcs[srow];
            int r1 = srcs[srow + 64];
            GLOAD16(&Xb[(size_t)r0 * DD + k0 + sq * 8], &As[srow][sq * 8]);
            GLOAD16(&Xb[(size_t)r1 * DD + k0 + sq * 8], &As[srow + 64][sq * 8]);
            GLOAD16(&WT[(size_t)(n0 + srow) * DD + k0 + sq * 8], &Bs[srow][sq * 8]);
            GLOAD16(&WT[(size_t)(n0 + srow + 64) * DD + k0 + sq * 8], &Bs[srow + 64][sq * 8]);
        }
        __syncthreads();
        short8 a[4], b[4];
#pragma unroll
        for (int mi = 0; mi < 4; ++mi)
            a[mi] = *(const short8*)&As[wr * 64 + mi * 16 + (lane & 15)][(lane >> 4) * 8];
#pragma unroll
        for (int ni = 0; ni < 4; ++ni)
            b[ni] = *(const short8*)&Bs[wc * 64 + ni * 16 + (lane & 15)][(lane >> 4) * 8];
#pragma unroll
        for (int mi = 0; mi < 4; ++mi)
#pragma unroll
            for (int ni = 0; ni < 4; ++ni)
                acc[mi][ni] = __builtin_amdgcn_mfma_f32_16x16x32_bf16(a[mi], b[ni], acc[mi][ni], 0, 0, 0);
        __syncthreads();
    }

    const int cq = lane >> 4;
    const int cn = lane & 15;
#pragma unroll
    for (int mi = 0; mi < 4; ++mi) {
#pragma unroll
        for (int q = 0; q < 4; ++q) {
            int slot = wr * 64 + mi * 16 + cq * 4 + q;
            if (slot < cnt) {
                int d = dsts[slot];
#pragma unroll
                for (int ni = 0; ni < 4; ++ni) {
                    int col = n0 + wc * 64 + ni * 16 + cn;
                    atomicAdd(&out[(size_t)d * DD + col], acc[mi][ni][q]);
                }
            }
        }
    }
}

extern "C" void kernel_launch(void* const* d_in, const int* in_sizes, int n_in,
                              void* d_out, int out_size, void* d_ws, size_t ws_size,
                              hipStream_t stream)
{
    const float* x      = (const float*)d_in[0];
    const int*   ei     = (const int*)d_in[1];   // [2][NE]: src row then dst row
    const int*   et     = (const int*)d_in[2];   // [NE]
    const float* W_rel  = (const float*)d_in[3]; // [NL][NREL][DD][DD]
    const float* W_root = (const float*)d_in[4]; // [NL][DD][DD]
    const float* bias   = (const float*)d_in[5]; // [NL][DD]
    float* out = (float*)d_out;

    unsigned short* xb     = (unsigned short*)d_ws;              // NN*DD bf16 (25.6 MB)
    unsigned short* wrelT  = xb + (size_t)NN * DD;               // NL*NREL*DD*DD bf16
    unsigned short* wrootT = wrelT + (size_t)NL * NREL * DD * DD;// NL*DD*DD bf16
    int* ssrc    = (int*)(wrootT + (size_t)NL * DD * DD);        // NE
    int* sdst    = ssrc + NE;                                    // NE
    int* offs    = sdst + NE;                                    // NREL+1
    int* bCounts = offs + NREL + 1;                              // NSB*NREL
    int* bOffs   = bCounts + NSB * NREL;                         // NSB*NREL

    // weights: transpose + bf16 (per call; deterministic)
    transpose_bf16<<<dim3(NL * NREL, DD / 32, DD / 32), dim3(32, 8), 0, stream>>>(W_rel, wrelT);
    transpose_bf16<<<dim3(NL, DD / 32, DD / 32), dim3(32, 8), 0, stream>>>(W_root, wrootT);
    // layer-0 input to bf16
    conv_bf16<<<2048, 256, 0, stream>>>((const float4*)x, (ushort4*)xb, NN * DD / 4);

    // contention-free counting sort of edges by relation
    hist_block<<<NSB, 256, 0, stream>>>(et, bCounts);
    scan_blocks<<<1, 64, 0, stream>>>(bCounts, bOffs, offs);
    scatter_block<<<NSB, 256, 0, stream>>>(ei, et, bOffs, ssrc, sdst);

    const int ntiles = (NE + 127) / 128 + NREL;  // upper bound on edge tiles

    for (int l = 0; l < NL; ++l) {
        root_gemm_mfma<<<dim3((NN + 127) / 128, DD / 128), 256, 0, stream>>>(
            xb, wrootT + (size_t)l * DD * DD, bias + (size_t)l * DD, out);
        edge_gemm_mfma<<<dim3(ntiles, DD / 128), 256, 0, stream>>>(
            xb, wrelT + (size_t)l * NREL * DD * DD, ssrc, sdst, offs, out);
        relu_convert<<<2048, 256, 0, stream>>>((float4*)out, (ushort4*)xb, NN * DD / 4);
    }
}

// Round 6
// 601.822 us; speedup vs baseline: 8.1968x; 1.3522x over previous
//
#include <hip/hip_runtime.h>

#define NN 50000      // nodes
#define NE 250000     // edges
#define DD 256        // feature dim
#define NREL 8        // relations
#define NL 3          // layers

#define NSRCB ((NN + 127) / 128)     // 391 src blocks
#define NBKT (NREL * NSRCB)          // 3128 sort buckets (rel, src>>7)

typedef __attribute__((ext_vector_type(8))) short short8;
typedef __attribute__((ext_vector_type(4))) float floatx4;

#if __has_builtin(__builtin_amdgcn_global_load_lds)
#define GLOAD16(g, l) __builtin_amdgcn_global_load_lds( \
    (__attribute__((address_space(1))) void*)(void*)(g), \
    (__attribute__((address_space(3))) void*)(void*)(l), 16, 0, 0)
#else
#define GLOAD16(g, l) do { *(uint4*)(l) = *(const uint4*)(g); } while (0)
#endif

__device__ inline unsigned short f2bf(float f) {
    unsigned int u = __builtin_bit_cast(unsigned int, f);
    u += 0x7FFFu + ((u >> 16) & 1u);          // round-to-nearest-even
    return (unsigned short)(u >> 16);
}
__device__ inline float bf2f(unsigned short u) {
    unsigned int x = ((unsigned int)u) << 16;
    return __builtin_bit_cast(float, x);
}

// ================= sort / index building =================
__global__ void zero_ints(int* __restrict__ p, int n) {
    int i = blockIdx.x * blockDim.x + threadIdx.x;
    if (i < n) p[i] = 0;
}

// histogram over (rel, srcblock)
__global__ void hist_bkt(const int* __restrict__ ei, const int* __restrict__ et,
                         int* __restrict__ bktCnt) {
    int e = blockIdx.x * blockDim.x + threadIdx.x;
    if (e < NE) atomicAdd(&bktCnt[et[e] * NSRCB + (ei[e] >> 7)], 1);
}

// exclusive scan of NBKT counts (1 block, 1024 threads); also rel offsets
__global__ void scan_bkt(const int* __restrict__ bktCnt, int* __restrict__ bktOff,
                         int* __restrict__ bktCur, int* __restrict__ relOffs) {
    __shared__ int ps[1024];
    const int t = threadIdx.x;
    const int CH = (NBKT + 1023) / 1024;   // 4
    const int base = t * CH;
    int s = 0;
#pragma unroll
    for (int i = 0; i < CH; ++i) if (base + i < NBKT) s += bktCnt[base + i];
    ps[t] = s;
    __syncthreads();
    for (int off = 1; off < 1024; off <<= 1) {
        int v = (t >= off) ? ps[t - off] : 0;
        __syncthreads();
        ps[t] += v;
        __syncthreads();
    }
    int run = (t == 0) ? 0 : ps[t - 1];
#pragma unroll
    for (int i = 0; i < CH; ++i)
        if (base + i < NBKT) { bktOff[base + i] = run; bktCur[base + i] = run; run += bktCnt[base + i]; }
    __syncthreads();
    if (t < NREL) relOffs[t] = bktOff[t * NSRCB];
    if (t == 0) relOffs[NREL] = NE;
}

__global__ void scatter_bkt(const int* __restrict__ ei, const int* __restrict__ et,
                            int* __restrict__ bktCur, int* __restrict__ ssrc,
                            int* __restrict__ sdst) {
    int e = blockIdx.x * blockDim.x + threadIdx.x;
    if (e < NE) {
        int s = ei[e];
        int p = atomicAdd(&bktCur[et[e] * NSRCB + (s >> 7)], 1);
        ssrc[p] = s;
        sdst[p] = ei[NE + e];
    }
}

// dst histogram over the sorted edge list
__global__ void hist_dst(const int* __restrict__ sdst, int* __restrict__ dstCnt) {
    int p = blockIdx.x * blockDim.x + threadIdx.x;
    if (p < NE) atomicAdd(&dstCnt[sdst[p]], 1);
}

// exclusive scan of NN dst counts (1 block, 1024 threads, 2-pass chunks)
__global__ void scan_dst(const int* __restrict__ dstCnt, int* __restrict__ dstOffs,
                         int* __restrict__ dstCur) {
    __shared__ int ps[1024];
    const int t = threadIdx.x;
    const int CH = (NN + 1023) / 1024;     // 49
    const int base = t * CH;
    int s = 0;
    for (int i = 0; i < CH; ++i) if (base + i < NN) s += dstCnt[base + i];
    ps[t] = s;
    __syncthreads();
    for (int off = 1; off < 1024; off <<= 1) {
        int v = (t >= off) ? ps[t - off] : 0;
        __syncthreads();
        ps[t] += v;
        __syncthreads();
    }
    int run = (t == 0) ? 0 : ps[t - 1];
    for (int i = 0; i < CH; ++i)
        if (base + i < NN) { dstOffs[base + i] = run; dstCur[base + i] = run; run += dstCnt[base + i]; }
    if (t == 0) dstOffs[NN] = NE;
}

// message slot for each sorted edge: position in dst-sorted order
__global__ void mk_mpos(const int* __restrict__ sdst, int* __restrict__ dstCur,
                        int* __restrict__ mpos) {
    int p = blockIdx.x * blockDim.x + threadIdx.x;
    if (p < NE) mpos[p] = atomicAdd(&dstCur[sdst[p]], 1);
}

// ============ weight transpose + fp32->bf16 (out[m][e][d] = in[m][d][e]) ============
__global__ void transpose_bf16(const float* __restrict__ src, unsigned short* __restrict__ dst) {
    __shared__ float t[32][33];
    const size_t mb = (size_t)blockIdx.x * DD * DD;
    const int d0 = blockIdx.y * 32, e0 = blockIdx.z * 32;
    const int tx = threadIdx.x, ty = threadIdx.y;
#pragma unroll
    for (int i = 0; i < 4; ++i)
        t[ty + 8 * i][tx] = src[mb + (size_t)(d0 + ty + 8 * i) * DD + e0 + tx];
    __syncthreads();
#pragma unroll
    for (int i = 0; i < 4; ++i)
        dst[mb + (size_t)(e0 + ty + 8 * i) * DD + d0 + tx] = f2bf(t[tx][ty + 8 * i]);
}

// ---------------- fp32 -> bf16 ----------------
__global__ void conv_bf16(const float4* __restrict__ s, ushort4* __restrict__ d, int n4) {
    int i = blockIdx.x * blockDim.x + threadIdx.x;
    const int stride = gridDim.x * blockDim.x;
    for (; i < n4; i += stride) {
        float4 v = s[i];
        d[i] = make_ushort4(f2bf(v.x), f2bf(v.y), f2bf(v.z), f2bf(v.w));
    }
}

// ---------------- relu in-place + bf16 copy (fallback path) ----------------
__global__ void relu_convert(float4* __restrict__ p, ushort4* __restrict__ xb, int n4) {
    int i = blockIdx.x * blockDim.x + threadIdx.x;
    const int stride = gridDim.x * blockDim.x;
    for (; i < n4; i += stride) {
        float4 v = p[i];
        v.x = v.x > 0.f ? v.x : 0.f;
        v.y = v.y > 0.f ? v.y : 0.f;
        v.z = v.z > 0.f ? v.z : 0.f;
        v.w = v.w > 0.f ? v.w : 0.f;
        p[i] = v;
        xb[i] = make_ushort4(f2bf(v.x), f2bf(v.y), f2bf(v.z), f2bf(v.w));
    }
}

// ---------------- root GEMM (MFMA): C = Xb @ WT + bias ----------------
__global__ __launch_bounds__(256)
void root_gemm_mfma(const unsigned short* __restrict__ Xb, const unsigned short* __restrict__ WT,
                    const float* __restrict__ bias, float* __restrict__ C)
{
    __shared__ unsigned short As[128][32];
    __shared__ unsigned short Bs[128][32];
    const int tid = threadIdx.x;
    const int lane = tid & 63;
    const int w = tid >> 6;
    const int wr = w >> 1, wc = w & 1;
    const int m0 = blockIdx.x * 128;
    const int n0 = blockIdx.y * 128;
    const int srow = tid >> 2;
    const int sq = tid & 3;

    floatx4 acc[4][4] = {};

    for (int kt = 0; kt < DD / 32; ++kt) {
        const int k0 = kt * 32;
        int r0 = min(m0 + srow, NN - 1);
        int r1 = min(m0 + srow + 64, NN - 1);
        GLOAD16(&Xb[(size_t)r0 * DD + k0 + sq * 8], &As[srow][sq * 8]);
        GLOAD16(&Xb[(size_t)r1 * DD + k0 + sq * 8], &As[srow + 64][sq * 8]);
        GLOAD16(&WT[(size_t)(n0 + srow) * DD + k0 + sq * 8], &Bs[srow][sq * 8]);
        GLOAD16(&WT[(size_t)(n0 + srow + 64) * DD + k0 + sq * 8], &Bs[srow + 64][sq * 8]);
        __syncthreads();
        short8 a[4], b[4];
#pragma unroll
        for (int mi = 0; mi < 4; ++mi)
            a[mi] = *(const short8*)&As[wr * 64 + mi * 16 + (lane & 15)][(lane >> 4) * 8];
#pragma unroll
        for (int ni = 0; ni < 4; ++ni)
            b[ni] = *(const short8*)&Bs[wc * 64 + ni * 16 + (lane & 15)][(lane >> 4) * 8];
#pragma unroll
        for (int mi = 0; mi < 4; ++mi)
#pragma unroll
            for (int ni = 0; ni < 4; ++ni)
                acc[mi][ni] = __builtin_amdgcn_mfma_f32_16x16x32_bf16(a[mi], b[ni], acc[mi][ni], 0, 0, 0);
        __syncthreads();
    }

    const int cq = lane >> 4;
    const int cn = lane & 15;
#pragma unroll
    for (int mi = 0; mi < 4; ++mi) {
#pragma unroll
        for (int q = 0; q < 4; ++q) {
            int row = m0 + wr * 64 + mi * 16 + cq * 4 + q;
            if (row < NN) {
#pragma unroll
                for (int ni = 0; ni < 4; ++ni) {
                    int col = n0 + wc * 64 + ni * 16 + cn;
                    C[(size_t)row * DD + col] = acc[mi][ni][q] + bias[col];
                }
            }
        }
    }
}

// ======== edge GEMM -> per-edge bf16 messages at dst-sorted slots (no atomics) ========
__global__ __launch_bounds__(256)
void edge_msgs(const unsigned short* __restrict__ Xb, const unsigned short* __restrict__ WTl,
               const int* __restrict__ ssrc, const int* __restrict__ mpos,
               const int* __restrict__ relOffs, unsigned short* __restrict__ msgs,
               int n0base, int MCOLS)
{
    __shared__ unsigned short As[128][32];
    __shared__ unsigned short Bs[128][32];
    __shared__ int srcs[128];
    __shared__ int mposs[128];

    const int t = blockIdx.x;
    int rel = -1, base = 0, cnt = 0, accT = 0;
#pragma unroll
    for (int r = 0; r < NREL; ++r) {
        int s = relOffs[r], e = relOffs[r + 1];
        int nt = (e - s + 127) / 128;
        if (rel < 0 && t < accT + nt) {
            rel = r;
            base = s + (t - accT) * 128;
            cnt = min(128, e - base);
        }
        accT += nt;
    }
    if (rel < 0) return;

    const int tid = threadIdx.x;
    if (tid < 128) {
        int idx = base + tid;
        srcs[tid] = (tid < cnt) ? ssrc[idx] : 0;
        mposs[tid] = (tid < cnt) ? mpos[idx] : 0;
    }
    __syncthreads();

    const unsigned short* WT = WTl + (size_t)rel * DD * DD;

    const int lane = tid & 63;
    const int w = tid >> 6;
    const int wr = w >> 1, wc = w & 1;
    const int n0 = n0base + blockIdx.y * 128;
    const int srow = tid >> 2;
    const int sq = tid & 3;

    floatx4 acc[4][4] = {};

    for (int kt = 0; kt < DD / 32; ++kt) {
        const int k0 = kt * 32;
        int r0 = srcs[srow];
        int r1 = srcs[srow + 64];
        GLOAD16(&Xb[(size_t)r0 * DD + k0 + sq * 8], &As[srow][sq * 8]);
        GLOAD16(&Xb[(size_t)r1 * DD + k0 + sq * 8], &As[srow + 64][sq * 8]);
        GLOAD16(&WT[(size_t)(n0 + srow) * DD + k0 + sq * 8], &Bs[srow][sq * 8]);
        GLOAD16(&WT[(size_t)(n0 + srow + 64) * DD + k0 + sq * 8], &Bs[srow + 64][sq * 8]);
        __syncthreads();
        short8 a[4], b[4];
#pragma unroll
        for (int mi = 0; mi < 4; ++mi)
            a[mi] = *(const short8*)&As[wr * 64 + mi * 16 + (lane & 15)][(lane >> 4) * 8];
#pragma unroll
        for (int ni = 0; ni < 4; ++ni)
            b[ni] = *(const short8*)&Bs[wc * 64 + ni * 16 + (lane & 15)][(lane >> 4) * 8];
#pragma unroll
        for (int mi = 0; mi < 4; ++mi)
#pragma unroll
            for (int ni = 0; ni < 4; ++ni)
                acc[mi][ni] = __builtin_amdgcn_mfma_f32_16x16x32_bf16(a[mi], b[ni], acc[mi][ni], 0, 0, 0);
        __syncthreads();
    }

    const int cq = lane >> 4;
    const int cn = lane & 15;
#pragma unroll
    for (int mi = 0; mi < 4; ++mi) {
#pragma unroll
        for (int q = 0; q < 4; ++q) {
            int slot = wr * 64 + mi * 16 + cq * 4 + q;
            if (slot < cnt) {
                size_t mrow = (size_t)mposs[slot] * MCOLS + blockIdx.y * 128 + wc * 64;
#pragma unroll
                for (int ni = 0; ni < 4; ++ni)
                    msgs[mrow + ni * 16 + cn] = f2bf(acc[mi][ni][q]);
            }
        }
    }
}

// ======== combine: out = relu(root + sum msgs), optional bf16 out for next layer ========
__global__ __launch_bounds__(256)
void combine4(const unsigned short* __restrict__ msgs, const int* __restrict__ dstOffs,
              float* __restrict__ out, unsigned short* __restrict__ xb)
{
    int v = blockIdx.x * 4 + (threadIdx.x >> 6);
    if (v >= NN) return;
    const int lane = threadIdx.x & 63;
    const size_t rb = (size_t)v * DD + lane * 4;
    float4 a = *(const float4*)&out[rb];
    const int b0 = dstOffs[v], b1 = dstOffs[v + 1];
    for (int k = b0; k < b1; ++k) {
        ushort4 m = *(const ushort4*)&msgs[(size_t)k * DD + lane * 4];
        a.x += bf2f(m.x); a.y += bf2f(m.y); a.z += bf2f(m.z); a.w += bf2f(m.w);
    }
    a.x = a.x > 0.f ? a.x : 0.f;
    a.y = a.y > 0.f ? a.y : 0.f;
    a.z = a.z > 0.f ? a.z : 0.f;
    a.w = a.w > 0.f ? a.w : 0.f;
    *(float4*)&out[rb] = a;
    *(ushort4*)&xb[rb] = make_ushort4(f2bf(a.x), f2bf(a.y), f2bf(a.z), f2bf(a.w));
}

__global__ __launch_bounds__(256)
void combine2(const unsigned short* __restrict__ msgs, const int* __restrict__ dstOffs,
              float* __restrict__ out, int colbase)
{
    int v = blockIdx.x * 4 + (threadIdx.x >> 6);
    if (v >= NN) return;
    const int lane = threadIdx.x & 63;
    const size_t rb = (size_t)v * DD + colbase + lane * 2;
    float2 a = *(const float2*)&out[rb];
    const int b0 = dstOffs[v], b1 = dstOffs[v + 1];
    for (int k = b0; k < b1; ++k) {
        ushort2 m = *(const ushort2*)&msgs[(size_t)k * 128 + lane * 2];
        a.x += bf2f(m.x); a.y += bf2f(m.y);
    }
    a.x = a.x > 0.f ? a.x : 0.f;
    a.y = a.y > 0.f ? a.y : 0.f;
    *(float2*)&out[rb] = a;
}

// ======== fallback: atomic-scatter edge GEMM (round-5 proven) ========
__global__ __launch_bounds__(256)
void edge_gemm_mfma(const unsigned short* __restrict__ Xb, const unsigned short* __restrict__ WTl,
                    const int* __restrict__ ssrc, const int* __restrict__ sdst,
                    const int* __restrict__ offsets, float* __restrict__ out)
{
    __shared__ unsigned short As[128][32];
    __shared__ unsigned short Bs[128][32];
    __shared__ int srcs[128];
    __shared__ int dsts[128];

    const int t = blockIdx.x;
    int rel = -1, base = 0, cnt = 0, accT = 0;
#pragma unroll
    for (int r = 0; r < NREL; ++r) {
        int s = offsets[r], e = offsets[r + 1];
        int nt = (e - s + 127) / 128;
        if (rel < 0 && t < accT + nt) {
            rel = r;
            base = s + (t - accT) * 128;
            cnt = min(128, e - base);
        }
        accT += nt;
    }
    if (rel < 0) return;

    const int tid = threadIdx.x;
    if (tid < 128) {
        int idx = base + tid;
        srcs[tid] = (tid < cnt) ? ssrc[idx] : 0;
        dsts[tid] = (tid < cnt) ? sdst[idx] : 0;
    }
    __syncthreads();

    const unsigned short* WT = WTl + (size_t)rel * DD * DD;
    const int lane = tid & 63;
    const int w = tid >> 6;
    const int wr = w >> 1, wc = w & 1;
    const int n0 = blockIdx.y * 128;
    const int srow = tid >> 2;
    const int sq = tid & 3;

    floatx4 acc[4][4] = {};

    for (int kt = 0; kt < DD / 32; ++kt) {
        const int k0 = kt * 32;
        int r0 = srcs[srow];
        int r1 = srcs[srow + 64];
        GLOAD16(&Xb[(size_t)r0 * DD + k0 + sq * 8], &As[srow][sq * 8]);
        GLOAD16(&Xb[(size_t)r1 * DD + k0 + sq * 8], &As[srow + 64][sq * 8]);
        GLOAD16(&WT[(size_t)(n0 + srow) * DD + k0 + sq * 8], &Bs[srow][sq * 8]);
        GLOAD16(&WT[(size_t)(n0 + srow + 64) * DD + k0 + sq * 8], &Bs[srow + 64][sq * 8]);
        __syncthreads();
        short8 a[4], b[4];
#pragma unroll
        for (int mi = 0; mi < 4; ++mi)
            a[mi] = *(const short8*)&As[wr * 64 + mi * 16 + (lane & 15)][(lane >> 4) * 8];
#pragma unroll
        for (int ni = 0; ni < 4; ++ni)
            b[ni] = *(const short8*)&Bs[wc * 64 + ni * 16 + (lane & 15)][(lane >> 4) * 8];
#pragma unroll
        for (int mi = 0; mi < 4; ++mi)
#pragma unroll
            for (int ni = 0; ni < 4; ++ni)
                acc[mi][ni] = __builtin_amdgcn_mfma_f32_16x16x32_bf16(a[mi], b[ni], acc[mi][ni], 0, 0, 0);
        __syncthreads();
    }

    const int cq = lane >> 4;
    const int cn = lane & 15;
#pragma unroll
    for (int mi = 0; mi < 4; ++mi) {
#pragma unroll
        for (int q = 0; q < 4; ++q) {
            int slot = wr * 64 + mi * 16 + cq * 4 + q;
            if (slot < cnt) {
                int d = dsts[slot];
#pragma unroll
                for (int ni = 0; ni < 4; ++ni) {
                    int col = n0 + wc * 64 + ni * 16 + cn;
                    atomicAdd(&out[(size_t)d * DD + col], acc[mi][ni][q]);
                }
            }
        }
    }
}

extern "C" void kernel_launch(void* const* d_in, const int* in_sizes, int n_in,
                              void* d_out, int out_size, void* d_ws, size_t ws_size,
                              hipStream_t stream)
{
    const float* x      = (const float*)d_in[0];
    const int*   ei     = (const int*)d_in[1];   // [2][NE]
    const int*   et     = (const int*)d_in[2];   // [NE]
    const float* W_rel  = (const float*)d_in[3]; // [NL][NREL][DD][DD]
    const float* W_root = (const float*)d_in[4]; // [NL][DD][DD]
    const float* bias   = (const float*)d_in[5]; // [NL][DD]
    float* out = (float*)d_out;

    unsigned char* wsb = (unsigned char*)d_ws;
    size_t off = 0;
    auto alloc = [&](size_t bytes) -> void* {
        void* p = wsb + off;
        off = (off + bytes + 255) & ~(size_t)255;
        return p;
    };
    unsigned short* xb      = (unsigned short*)alloc((size_t)NN * DD * 2);
    unsigned short* wrelT   = (unsigned short*)alloc((size_t)NL * NREL * DD * DD * 2);
    unsigned short* wrootT  = (unsigned short*)alloc((size_t)NL * DD * DD * 2);
    int* ssrc    = (int*)alloc((size_t)NE * 4);
    int* sdst    = (int*)alloc((size_t)NE * 4);
    int* mpos    = (int*)alloc((size_t)NE * 4);
    int* dstOffs = (int*)alloc((size_t)(NN + 1) * 4);
    int* dstCnt  = (int*)alloc((size_t)NN * 4);
    int* dstCur  = (int*)alloc((size_t)NN * 4);
    int* bktCnt  = (int*)alloc((size_t)NBKT * 4);
    int* bktOff  = (int*)alloc((size_t)NBKT * 4);
    int* bktCur  = (int*)alloc((size_t)NBKT * 4);
    int* relOffs = (int*)alloc((size_t)(NREL + 1) * 4);
    unsigned short* msgs = (unsigned short*)(wsb + off);
    const size_t cap = (ws_size > off) ? ws_size - off : 0;
    const size_t needFull = (size_t)NE * DD * 2;   // 128 MB
    // mode: 1 = full msg buffer, 2 = col-split halves, 0 = atomic fallback
    const int mode = (cap >= needFull) ? 1 : (cap >= needFull / 2) ? 2 : 0;

    // weights: transpose + bf16
    transpose_bf16<<<dim3(NL * NREL, DD / 32, DD / 32), dim3(32, 8), 0, stream>>>(W_rel, wrelT);
    transpose_bf16<<<dim3(NL, DD / 32, DD / 32), dim3(32, 8), 0, stream>>>(W_root, wrootT);
    conv_bf16<<<2048, 256, 0, stream>>>((const float4*)x, (ushort4*)xb, NN * DD / 4);

    // counting sort by (rel, srcblock)
    zero_ints<<<(NBKT + 255) / 256, 256, 0, stream>>>(bktCnt, NBKT);
    hist_bkt<<<(NE + 255) / 256, 256, 0, stream>>>(ei, et, bktCnt);
    scan_bkt<<<1, 1024, 0, stream>>>(bktCnt, bktOff, bktCur, relOffs);
    scatter_bkt<<<(NE + 255) / 256, 256, 0, stream>>>(ei, et, bktCur, ssrc, sdst);

    if (mode != 0) {
        zero_ints<<<(NN + 255) / 256, 256, 0, stream>>>(dstCnt, NN);
        hist_dst<<<(NE + 255) / 256, 256, 0, stream>>>(sdst, dstCnt);
        scan_dst<<<1, 1024, 0, stream>>>(dstCnt, dstOffs, dstCur);
        mk_mpos<<<(NE + 255) / 256, 256, 0, stream>>>(sdst, dstCur, mpos);
    }

    const int ntiles = (NE + 127) / 128 + NREL;
    const int ncomb = (NN + 3) / 4;

    for (int l = 0; l < NL; ++l) {
        root_gemm_mfma<<<dim3((NN + 127) / 128, DD / 128), 256, 0, stream>>>(
            xb, wrootT + (size_t)l * DD * DD, bias + (size_t)l * DD, out);
        const unsigned short* wl = wrelT + (size_t)l * NREL * DD * DD;
        if (mode == 1) {
            edge_msgs<<<dim3(ntiles, 2), 256, 0, stream>>>(
                xb, wl, ssrc, mpos, relOffs, msgs, 0, DD);
            combine4<<<ncomb, 256, 0, stream>>>(msgs, dstOffs, out, xb);
        } else if (mode == 2) {
            for (int h = 0; h < 2; ++h) {
                edge_msgs<<<dim3(ntiles, 1), 256, 0, stream>>>(
                    xb, wl, ssrc, mpos, relOffs, msgs, h * 128, 128);
                combine2<<<ncomb, 256, 0, stream>>>(msgs, dstOffs, out, h * 128);
            }
            conv_bf16<<<2048, 256, 0, stream>>>((const float4*)out, (ushort4*)xb, NN * DD / 4);
        } else {
            edge_gemm_mfma<<<dim3(ntiles, DD / 128), 256, 0, stream>>>(
                xb, wl, ssrc, sdst, relOffs, out);
            relu_convert<<<2048, 256, 0, stream>>>((float4*)out, (ushort4*)xb, NN * DD / 4);
        }
    }
}

// Round 7
// 491.308 us; speedup vs baseline: 10.0405x; 1.2249x over previous
//
#include <hip/hip_runtime.h>

#define NN 50000      // nodes
#define NE 250000     // edges
#define DD 256        // feature dim
#define NREL 8        // relations
#define NL 3          // layers

#define NSRCB ((NN + 127) / 128)     // 391 src blocks
#define NBKT (NREL * NSRCB)          // 3128 sort buckets (rel, src>>7)

typedef __attribute__((ext_vector_type(8))) short short8;
typedef __attribute__((ext_vector_type(4))) float floatx4;

#if __has_builtin(__builtin_amdgcn_global_load_lds)
#define GLOAD16(g, l) __builtin_amdgcn_global_load_lds( \
    (__attribute__((address_space(1))) void*)(void*)(g), \
    (__attribute__((address_space(3))) void*)(void*)(l), 16, 0, 0)
#else
#define GLOAD16(g, l) do { *(uint4*)(l) = *(const uint4*)(g); } while (0)
#endif

__device__ inline unsigned short f2bf(float f) {
    unsigned int u = __builtin_bit_cast(unsigned int, f);
    u += 0x7FFFu + ((u >> 16) & 1u);          // round-to-nearest-even
    return (unsigned short)(u >> 16);
}
__device__ inline float bf2f(unsigned short u) {
    unsigned int x = ((unsigned int)u) << 16;
    return __builtin_bit_cast(float, x);
}

// ================= sort / index building =================
__global__ void zero_ints(int* __restrict__ p, int n) {
    int i = blockIdx.x * blockDim.x + threadIdx.x;
    if (i < n) p[i] = 0;
}

// histogram over (rel, srcblock)
__global__ void hist_bkt(const int* __restrict__ ei, const int* __restrict__ et,
                         int* __restrict__ bktCnt) {
    int e = blockIdx.x * blockDim.x + threadIdx.x;
    if (e < NE) atomicAdd(&bktCnt[et[e] * NSRCB + (ei[e] >> 7)], 1);
}

// ---- hierarchical exclusive scan: part-sums -> top scan -> local scan ----
__global__ __launch_bounds__(256)
void scan_part(const int* __restrict__ cnt, int n, int* __restrict__ blockSums) {
    __shared__ int ps[256];
    const int b = blockIdx.x, t = threadIdx.x;
    const int base = b * 1024 + t * 4;
    int s = 0;
#pragma unroll
    for (int j = 0; j < 4; ++j) s += (base + j < n) ? cnt[base + j] : 0;
    ps[t] = s;
    __syncthreads();
    for (int o = 128; o > 0; o >>= 1) {
        if (t < o) ps[t] += ps[t + o];
        __syncthreads();
    }
    if (t == 0) blockSums[b] = ps[0];
}

__global__ __launch_bounds__(256)
void scan_tops(const int* __restrict__ blockSums, int nb, int* __restrict__ blockOffs) {
    __shared__ int ps[256];
    const int t = threadIdx.x;
    ps[t] = (t < nb) ? blockSums[t] : 0;
    __syncthreads();
    for (int o = 1; o < 256; o <<= 1) {
        int x = (t >= o) ? ps[t - o] : 0;
        __syncthreads();
        ps[t] += x;
        __syncthreads();
    }
    blockOffs[t] = (t == 0) ? 0 : ps[t - 1];
}

__global__ __launch_bounds__(256)
void scan_local(const int* __restrict__ cnt, int n, int total,
                const int* __restrict__ blockOffs,
                int* __restrict__ offs, int* __restrict__ cur) {
    __shared__ int ps[256];
    const int b = blockIdx.x, t = threadIdx.x;
    const int base = b * 1024 + t * 4;
    int v[4];
#pragma unroll
    for (int j = 0; j < 4; ++j) v[j] = (base + j < n) ? cnt[base + j] : 0;
    int s = v[0] + v[1] + v[2] + v[3];
    ps[t] = s;
    __syncthreads();
    for (int o = 1; o < 256; o <<= 1) {
        int x = (t >= o) ? ps[t - o] : 0;
        __syncthreads();
        ps[t] += x;
        __syncthreads();
    }
    int run = blockOffs[b] + ((t == 0) ? 0 : ps[t - 1]);
#pragma unroll
    for (int j = 0; j < 4; ++j) {
        if (base + j < n) { offs[base + j] = run; cur[base + j] = run; run += v[j]; }
    }
    if (b == 0 && t == 0) offs[n] = total;
}

__global__ void mk_reloffs(const int* __restrict__ bktOff, int* __restrict__ relOffs) {
    const int t = threadIdx.x;
    if (t < NREL) relOffs[t] = bktOff[t * NSRCB];
    if (t == 0) relOffs[NREL] = NE;
}

__global__ void scatter_bkt(const int* __restrict__ ei, const int* __restrict__ et,
                            int* __restrict__ bktCur, int* __restrict__ ssrc,
                            int* __restrict__ sdst) {
    int e = blockIdx.x * blockDim.x + threadIdx.x;
    if (e < NE) {
        int s = ei[e];
        int p = atomicAdd(&bktCur[et[e] * NSRCB + (s >> 7)], 1);
        ssrc[p] = s;
        sdst[p] = ei[NE + e];
    }
}

// dst histogram over the sorted edge list
__global__ void hist_dst(const int* __restrict__ sdst, int* __restrict__ dstCnt) {
    int p = blockIdx.x * blockDim.x + threadIdx.x;
    if (p < NE) atomicAdd(&dstCnt[sdst[p]], 1);
}

// message slot for each sorted edge: position in dst-sorted order
__global__ void mk_mpos(const int* __restrict__ sdst, int* __restrict__ dstCur,
                        int* __restrict__ mpos) {
    int p = blockIdx.x * blockDim.x + threadIdx.x;
    if (p < NE) mpos[p] = atomicAdd(&dstCur[sdst[p]], 1);
}

// ============ weight transpose + fp32->bf16 (out[m][e][d] = in[m][d][e]) ============
__global__ void transpose_bf16(const float* __restrict__ src, unsigned short* __restrict__ dst) {
    __shared__ float t[32][33];
    const size_t mb = (size_t)blockIdx.x * DD * DD;
    const int d0 = blockIdx.y * 32, e0 = blockIdx.z * 32;
    const int tx = threadIdx.x, ty = threadIdx.y;
#pragma unroll
    for (int i = 0; i < 4; ++i)
        t[ty + 8 * i][tx] = src[mb + (size_t)(d0 + ty + 8 * i) * DD + e0 + tx];
    __syncthreads();
#pragma unroll
    for (int i = 0; i < 4; ++i)
        dst[mb + (size_t)(e0 + ty + 8 * i) * DD + d0 + tx] = f2bf(t[tx][ty + 8 * i]);
}

// ---------------- fp32 -> bf16 ----------------
__global__ void conv_bf16(const float4* __restrict__ s, ushort4* __restrict__ d, int n4) {
    int i = blockIdx.x * blockDim.x + threadIdx.x;
    const int stride = gridDim.x * blockDim.x;
    for (; i < n4; i += stride) {
        float4 v = s[i];
        d[i] = make_ushort4(f2bf(v.x), f2bf(v.y), f2bf(v.z), f2bf(v.w));
    }
}

// ---------------- relu in-place + bf16 copy (fallback path) ----------------
__global__ void relu_convert(float4* __restrict__ p, ushort4* __restrict__ xb, int n4) {
    int i = blockIdx.x * blockDim.x + threadIdx.x;
    const int stride = gridDim.x * blockDim.x;
    for (; i < n4; i += stride) {
        float4 v = p[i];
        v.x = v.x > 0.f ? v.x : 0.f;
        v.y = v.y > 0.f ? v.y : 0.f;
        v.z = v.z > 0.f ? v.z : 0.f;
        v.w = v.w > 0.f ? v.w : 0.f;
        p[i] = v;
        xb[i] = make_ushort4(f2bf(v.x), f2bf(v.y), f2bf(v.z), f2bf(v.w));
    }
}

// ---------------- root GEMM (MFMA): C = Xb @ WT + bias ----------------
__global__ __launch_bounds__(256)
void root_gemm_mfma(const unsigned short* __restrict__ Xb, const unsigned short* __restrict__ WT,
                    const float* __restrict__ bias, float* __restrict__ C)
{
    __shared__ unsigned short As[128][32];
    __shared__ unsigned short Bs[128][32];
    const int tid = threadIdx.x;
    const int lane = tid & 63;
    const int w = tid >> 6;
    const int wr = w >> 1, wc = w & 1;
    const int m0 = blockIdx.x * 128;
    const int n0 = blockIdx.y * 128;
    const int srow = tid >> 2;
    const int sq = tid & 3;

    floatx4 acc[4][4] = {};

    for (int kt = 0; kt < DD / 32; ++kt) {
        const int k0 = kt * 32;
        int r0 = min(m0 + srow, NN - 1);
        int r1 = min(m0 + srow + 64, NN - 1);
        GLOAD16(&Xb[(size_t)r0 * DD + k0 + sq * 8], &As[srow][sq * 8]);
        GLOAD16(&Xb[(size_t)r1 * DD + k0 + sq * 8], &As[srow + 64][sq * 8]);
        GLOAD16(&WT[(size_t)(n0 + srow) * DD + k0 + sq * 8], &Bs[srow][sq * 8]);
        GLOAD16(&WT[(size_t)(n0 + srow + 64) * DD + k0 + sq * 8], &Bs[srow + 64][sq * 8]);
        __syncthreads();
        short8 a[4], b[4];
#pragma unroll
        for (int mi = 0; mi < 4; ++mi)
            a[mi] = *(const short8*)&As[wr * 64 + mi * 16 + (lane & 15)][(lane >> 4) * 8];
#pragma unroll
        for (int ni = 0; ni < 4; ++ni)
            b[ni] = *(const short8*)&Bs[wc * 64 + ni * 16 + (lane & 15)][(lane >> 4) * 8];
#pragma unroll
        for (int mi = 0; mi < 4; ++mi)
#pragma unroll
            for (int ni = 0; ni < 4; ++ni)
                acc[mi][ni] = __builtin_amdgcn_mfma_f32_16x16x32_bf16(a[mi], b[ni], acc[mi][ni], 0, 0, 0);
        __syncthreads();
    }

    const int cq = lane >> 4;
    const int cn = lane & 15;
#pragma unroll
    for (int mi = 0; mi < 4; ++mi) {
#pragma unroll
        for (int q = 0; q < 4; ++q) {
            int row = m0 + wr * 64 + mi * 16 + cq * 4 + q;
            if (row < NN) {
#pragma unroll
                for (int ni = 0; ni < 4; ++ni) {
                    int col = n0 + wc * 64 + ni * 16 + cn;
                    C[(size_t)row * DD + col] = acc[mi][ni][q] + bias[col];
                }
            }
        }
    }
}

// ======== edge GEMM -> per-edge bf16 messages at dst-sorted slots (no atomics) ========
__global__ __launch_bounds__(256)
void edge_msgs(const unsigned short* __restrict__ Xb, const unsigned short* __restrict__ WTl,
               const int* __restrict__ ssrc, const int* __restrict__ mpos,
               const int* __restrict__ relOffs, unsigned short* __restrict__ msgs,
               int n0base, int MCOLS)
{
    __shared__ unsigned short As[128][32];
    __shared__ unsigned short Bs[128][32];
    __shared__ int srcs[128];
    __shared__ int mposs[128];

    const int t = blockIdx.x;
    int rel = -1, base = 0, cnt = 0, accT = 0;
#pragma unroll
    for (int r = 0; r < NREL; ++r) {
        int s = relOffs[r], e = relOffs[r + 1];
        int nt = (e - s + 127) / 128;
        if (rel < 0 && t < accT + nt) {
            rel = r;
            base = s + (t - accT) * 128;
            cnt = min(128, e - base);
        }
        accT += nt;
    }
    if (rel < 0) return;

    const int tid = threadIdx.x;
    if (tid < 128) {
        int idx = base + tid;
        srcs[tid] = (tid < cnt) ? ssrc[idx] : 0;
        mposs[tid] = (tid < cnt) ? mpos[idx] : 0;
    }
    __syncthreads();

    const unsigned short* WT = WTl + (size_t)rel * DD * DD;

    const int lane = tid & 63;
    const int w = tid >> 6;
    const int wr = w >> 1, wc = w & 1;
    const int n0 = n0base + blockIdx.y * 128;
    const int srow = tid >> 2;
    const int sq = tid & 3;

    floatx4 acc[4][4] = {};

    for (int kt = 0; kt < DD / 32; ++kt) {
        const int k0 = kt * 32;
        int r0 = srcs[srow];
        int r1 = srcs[srow + 64];
        GLOAD16(&Xb[(size_t)r0 * DD + k0 + sq * 8], &As[srow][sq * 8]);
        GLOAD16(&Xb[(size_t)r1 * DD + k0 + sq * 8], &As[srow + 64][sq * 8]);
        GLOAD16(&WT[(size_t)(n0 + srow) * DD + k0 + sq * 8], &Bs[srow][sq * 8]);
        GLOAD16(&WT[(size_t)(n0 + srow + 64) * DD + k0 + sq * 8], &Bs[srow + 64][sq * 8]);
        __syncthreads();
        short8 a[4], b[4];
#pragma unroll
        for (int mi = 0; mi < 4; ++mi)
            a[mi] = *(const short8*)&As[wr * 64 + mi * 16 + (lane & 15)][(lane >> 4) * 8];
#pragma unroll
        for (int ni = 0; ni < 4; ++ni)
            b[ni] = *(const short8*)&Bs[wc * 64 + ni * 16 + (lane & 15)][(lane >> 4) * 8];
#pragma unroll
        for (int mi = 0; mi < 4; ++mi)
#pragma unroll
            for (int ni = 0; ni < 4; ++ni)
                acc[mi][ni] = __builtin_amdgcn_mfma_f32_16x16x32_bf16(a[mi], b[ni], acc[mi][ni], 0, 0, 0);
        __syncthreads();
    }

    const int cq = lane >> 4;
    const int cn = lane & 15;
#pragma unroll
    for (int mi = 0; mi < 4; ++mi) {
#pragma unroll
        for (int q = 0; q < 4; ++q) {
            int slot = wr * 64 + mi * 16 + cq * 4 + q;
            if (slot < cnt) {
                size_t mrow = (size_t)mposs[slot] * MCOLS + blockIdx.y * 128 + wc * 64;
#pragma unroll
                for (int ni = 0; ni < 4; ++ni)
                    msgs[mrow + ni * 16 + cn] = f2bf(acc[mi][ni][q]);
            }
        }
    }
}

// ======== combine: out = relu(root + sum msgs), bf16 out for next layer ========
__global__ __launch_bounds__(256)
void combine4(const unsigned short* __restrict__ msgs, const int* __restrict__ dstOffs,
              float* __restrict__ out, unsigned short* __restrict__ xb)
{
    int v = blockIdx.x * 4 + (threadIdx.x >> 6);
    if (v >= NN) return;
    const int lane = threadIdx.x & 63;
    const size_t rb = (size_t)v * DD + lane * 4;
    float4 a = *(const float4*)&out[rb];
    const int b0 = dstOffs[v], b1 = dstOffs[v + 1];
    for (int k = b0; k < b1; ++k) {
        ushort4 m = *(const ushort4*)&msgs[(size_t)k * DD + lane * 4];
        a.x += bf2f(m.x); a.y += bf2f(m.y); a.z += bf2f(m.z); a.w += bf2f(m.w);
    }
    a.x = a.x > 0.f ? a.x : 0.f;
    a.y = a.y > 0.f ? a.y : 0.f;
    a.z = a.z > 0.f ? a.z : 0.f;
    a.w = a.w > 0.f ? a.w : 0.f;
    *(float4*)&out[rb] = a;
    *(ushort4*)&xb[rb] = make_ushort4(f2bf(a.x), f2bf(a.y), f2bf(a.z), f2bf(a.w));
}

__global__ __launch_bounds__(256)
void combine2(const unsigned short* __restrict__ msgs, const int* __restrict__ dstOffs,
              float* __restrict__ out, int colbase)
{
    int v = blockIdx.x * 4 + (threadIdx.x >> 6);
    if (v >= NN) return;
    const int lane = threadIdx.x & 63;
    const size_t rb = (size_t)v * DD + colbase + lane * 2;
    float2 a = *(const float2*)&out[rb];
    const int b0 = dstOffs[v], b1 = dstOffs[v + 1];
    for (int k = b0; k < b1; ++k) {
        ushort2 m = *(const ushort2*)&msgs[(size_t)k * 128 + lane * 2];
        a.x += bf2f(m.x); a.y += bf2f(m.y);
    }
    a.x = a.x > 0.f ? a.x : 0.f;
    a.y = a.y > 0.f ? a.y : 0.f;
    *(float2*)&out[rb] = a;
}

// ======== fallback: atomic-scatter edge GEMM (round-5 proven) ========
__global__ __launch_bounds__(256)
void edge_gemm_mfma(const unsigned short* __restrict__ Xb, const unsigned short* __restrict__ WTl,
                    const int* __restrict__ ssrc, const int* __restrict__ sdst,
                    const int* __restrict__ offsets, float* __restrict__ out)
{
    __shared__ unsigned short As[128][32];
    __shared__ unsigned short Bs[128][32];
    __shared__ int srcs[128];
    __shared__ int dsts[128];

    const int t = blockIdx.x;
    int rel = -1, base = 0, cnt = 0, accT = 0;
#pragma unroll
    for (int r = 0; r < NREL; ++r) {
        int s = offsets[r], e = offsets[r + 1];
        int nt = (e - s + 127) / 128;
        if (rel < 0 && t < accT + nt) {
            rel = r;
            base = s + (t - accT) * 128;
            cnt = min(128, e - base);
        }
        accT += nt;
    }
    if (rel < 0) return;

    const int tid = threadIdx.x;
    if (tid < 128) {
        int idx = base + tid;
        srcs[tid] = (tid < cnt) ? ssrc[idx] : 0;
        dsts[tid] = (tid < cnt) ? sdst[idx] : 0;
    }
    __syncthreads();

    const unsigned short* WT = WTl + (size_t)rel * DD * DD;
    const int lane = tid & 63;
    const int w = tid >> 6;
    const int wr = w >> 1, wc = w & 1;
    const int n0 = blockIdx.y * 128;
    const int srow = tid >> 2;
    const int sq = tid & 3;

    floatx4 acc[4][4] = {};

    for (int kt = 0; kt < DD / 32; ++kt) {
        const int k0 = kt * 32;
        int r0 = srcs[srow];
        int r1 = srcs[srow + 64];
        GLOAD16(&Xb[(size_t)r0 * DD + k0 + sq * 8], &As[srow][sq * 8]);
        GLOAD16(&Xb[(size_t)r1 * DD + k0 + sq * 8], &As[srow + 64][sq * 8]);
        GLOAD16(&WT[(size_t)(n0 + srow) * DD + k0 + sq * 8], &Bs[srow][sq * 8]);
        GLOAD16(&WT[(size_t)(n0 + srow + 64) * DD + k0 + sq * 8], &Bs[srow + 64][sq * 8]);
        __syncthreads();
        short8 a[4], b[4];
#pragma unroll
        for (int mi = 0; mi < 4; ++mi)
            a[mi] = *(const short8*)&As[wr * 64 + mi * 16 + (lane & 15)][(lane >> 4) * 8];
#pragma unroll
        for (int ni = 0; ni < 4; ++ni)
            b[ni] = *(const short8*)&Bs[wc * 64 + ni * 16 + (lane & 15)][(lane >> 4) * 8];
#pragma unroll
        for (int mi = 0; mi < 4; ++mi)
#pragma unroll
            for (int ni = 0; ni < 4; ++ni)
                acc[mi][ni] = __builtin_amdgcn_mfma_f32_16x16x32_bf16(a[mi], b[ni], acc[mi][ni], 0, 0, 0);
        __syncthreads();
    }

    const int cq = lane >> 4;
    const int cn = lane & 15;
#pragma unroll
    for (int mi = 0; mi < 4; ++mi) {
#pragma unroll
        for (int q = 0; q < 4; ++q) {
            int slot = wr * 64 + mi * 16 + cq * 4 + q;
            if (slot < cnt) {
                int d = dsts[slot];
#pragma unroll
                for (int ni = 0; ni < 4; ++ni) {
                    int col = n0 + wc * 64 + ni * 16 + cn;
                    atomicAdd(&out[(size_t)d * DD + col], acc[mi][ni][q]);
                }
            }
        }
    }
}

extern "C" void kernel_launch(void* const* d_in, const int* in_sizes, int n_in,
                              void* d_out, int out_size, void* d_ws, size_t ws_size,
                              hipStream_t stream)
{
    const float* x      = (const float*)d_in[0];
    const int*   ei     = (const int*)d_in[1];   // [2][NE]
    const int*   et     = (const int*)d_in[2];   // [NE]
    const float* W_rel  = (const float*)d_in[3]; // [NL][NREL][DD][DD]
    const float* W_root = (const float*)d_in[4]; // [NL][DD][DD]
    const float* bias   = (const float*)d_in[5]; // [NL][DD]
    float* out = (float*)d_out;

    unsigned char* wsb = (unsigned char*)d_ws;
    size_t off = 0;
    auto alloc = [&](size_t bytes) -> void* {
        void* p = wsb + off;
        off = (off + bytes + 255) & ~(size_t)255;
        return p;
    };
    unsigned short* xb      = (unsigned short*)alloc((size_t)NN * DD * 2);
    unsigned short* wrelT   = (unsigned short*)alloc((size_t)NL * NREL * DD * DD * 2);
    unsigned short* wrootT  = (unsigned short*)alloc((size_t)NL * DD * DD * 2);
    int* ssrc    = (int*)alloc((size_t)NE * 4);
    int* sdst    = (int*)alloc((size_t)NE * 4);
    int* mpos    = (int*)alloc((size_t)NE * 4);
    int* dstOffs = (int*)alloc((size_t)(NN + 1) * 4);
    int* dstCnt  = (int*)alloc((size_t)NN * 4);
    int* dstCur  = (int*)alloc((size_t)NN * 4);
    int* bktCnt  = (int*)alloc((size_t)NBKT * 4);
    int* bktOff  = (int*)alloc((size_t)(NBKT + 1) * 4);
    int* bktCur  = (int*)alloc((size_t)NBKT * 4);
    int* relOffs = (int*)alloc((size_t)(NREL + 1) * 4);
    int* bktSums = (int*)alloc(256 * 4);
    int* bktBOff = (int*)alloc(256 * 4);
    int* dstSums = (int*)alloc(256 * 4);
    int* dstBOff = (int*)alloc(256 * 4);
    unsigned short* msgs = (unsigned short*)(wsb + off);
    const size_t cap = (ws_size > off) ? ws_size - off : 0;
    const size_t needFull = (size_t)NE * DD * 2;   // 128 MB
    // mode: 1 = full msg buffer, 2 = col-split halves, 0 = atomic fallback
    const int mode = (cap >= needFull) ? 1 : (cap >= needFull / 2) ? 2 : 0;

    const int nbBkt = (NBKT + 1023) / 1024;   // 4
    const int nbDst = (NN + 1023) / 1024;     // 49

    // weights: transpose + bf16
    transpose_bf16<<<dim3(NL * NREL, DD / 32, DD / 32), dim3(32, 8), 0, stream>>>(W_rel, wrelT);
    transpose_bf16<<<dim3(NL, DD / 32, DD / 32), dim3(32, 8), 0, stream>>>(W_root, wrootT);
    conv_bf16<<<2048, 256, 0, stream>>>((const float4*)x, (ushort4*)xb, NN * DD / 4);

    // counting sort by (rel, srcblock), hierarchical scan
    zero_ints<<<(NBKT + 255) / 256, 256, 0, stream>>>(bktCnt, NBKT);
    hist_bkt<<<(NE + 255) / 256, 256, 0, stream>>>(ei, et, bktCnt);
    scan_part<<<nbBkt, 256, 0, stream>>>(bktCnt, NBKT, bktSums);
    scan_tops<<<1, 256, 0, stream>>>(bktSums, nbBkt, bktBOff);
    scan_local<<<nbBkt, 256, 0, stream>>>(bktCnt, NBKT, NE, bktBOff, bktOff, bktCur);
    mk_reloffs<<<1, 64, 0, stream>>>(bktOff, relOffs);
    scatter_bkt<<<(NE + 255) / 256, 256, 0, stream>>>(ei, et, bktCur, ssrc, sdst);

    if (mode != 0) {
        zero_ints<<<(NN + 255) / 256, 256, 0, stream>>>(dstCnt, NN);
        hist_dst<<<(NE + 255) / 256, 256, 0, stream>>>(sdst, dstCnt);
        scan_part<<<nbDst, 256, 0, stream>>>(dstCnt, NN, dstSums);
        scan_tops<<<1, 256, 0, stream>>>(dstSums, nbDst, dstBOff);
        scan_local<<<nbDst, 256, 0, stream>>>(dstCnt, NN, NE, dstBOff, dstOffs, dstCur);
        mk_mpos<<<(NE + 255) / 256, 256, 0, stream>>>(sdst, dstCur, mpos);
    }

    const int ntiles = (NE + 127) / 128 + NREL;
    const int ncomb = (NN + 3) / 4;

    for (int l = 0; l < NL; ++l) {
        root_gemm_mfma<<<dim3((NN + 127) / 128, DD / 128), 256, 0, stream>>>(
            xb, wrootT + (size_t)l * DD * DD, bias + (size_t)l * DD, out);
        const unsigned short* wl = wrelT + (size_t)l * NREL * DD * DD;
        if (mode == 1) {
            edge_msgs<<<dim3(ntiles, 2), 256, 0, stream>>>(
                xb, wl, ssrc, mpos, relOffs, msgs, 0, DD);
            combine4<<<ncomb, 256, 0, stream>>>(msgs, dstOffs, out, xb);
        } else if (mode == 2) {
            for (int h = 0; h < 2; ++h) {
                edge_msgs<<<dim3(ntiles, 1), 256, 0, stream>>>(
                    xb, wl, ssrc, mpos, relOffs, msgs, h * 128, 128);
                combine2<<<ncomb, 256, 0, stream>>>(msgs, dstOffs, out, h * 128);
            }
            conv_bf16<<<2048, 256, 0, stream>>>((const float4*)out, (ushort4*)xb, NN * DD / 4);
        } else {
            edge_gemm_mfma<<<dim3(ntiles, DD / 128), 256, 0, stream>>>(
                xb, wl, ssrc, sdst, relOffs, out);
            relu_convert<<<2048, 256, 0, stream>>>((float4*)out, (ushort4*)xb, NN * DD / 4);
        }
    }
}